// Round 5
// baseline (229.319 us; speedup 1.0000x reference)
//
#include <hip/hip_runtime.h>
#include <stdint.h>

#define N 8192
#define D 256          // elements per row == bytes per fp8 row == full K
#define INV_T 20.0f
#define BM 128
#define BN 128
#define BK 128

typedef __attribute__((ext_vector_type(4))) int i32x4;
typedef __attribute__((ext_vector_type(8))) int i32x8;
typedef __attribute__((ext_vector_type(4))) float f32x4;

typedef __attribute__((address_space(3))) uint32_t lds_u32;
typedef __attribute__((address_space(1))) const uint32_t gbl_u32;

// Kernel 1: per-row fp32 normalize -> fp8 e4m3 (OCP) copies; c[i]=(e_i.p_i)/T exact fp32.
// Also zeroes out[0] (poisoned 0xAA; reduce kernel atomicAdds into it).
__global__ __launch_bounds__(256) void normalize_kernel(
    const float* __restrict__ e, const float* __restrict__ p, const float* __restrict__ n,
    uint32_t* __restrict__ eb, uint32_t* __restrict__ pb, uint32_t* __restrict__ nb,
    float* __restrict__ cbuf, float* __restrict__ out0) {
  const int tid = threadIdx.x;
  const int wave = tid >> 6, lane = tid & 63;
  const int row = blockIdx.x * 4 + wave;          // one wave per row
  if (blockIdx.x == 0 && tid == 0) out0[0] = 0.0f;

  const float4 ev = ((const float4*)(e + (size_t)row * D))[lane];
  const float4 pv = ((const float4*)(p + (size_t)row * D))[lane];
  const float4 nv = ((const float4*)(n + (size_t)row * D))[lane];

  float sse = ev.x*ev.x + ev.y*ev.y + ev.z*ev.z + ev.w*ev.w;
  float ssp = pv.x*pv.x + pv.y*pv.y + pv.z*pv.z + pv.w*pv.w;
  float ssn = nv.x*nv.x + nv.y*nv.y + nv.z*nv.z + nv.w*nv.w;
  float dep = ev.x*pv.x + ev.y*pv.y + ev.z*pv.z + ev.w*pv.w;
#pragma unroll
  for (int m = 1; m < 64; m <<= 1) {
    sse += __shfl_xor(sse, m);
    ssp += __shfl_xor(ssp, m);
    ssn += __shfl_xor(ssn, m);
    dep += __shfl_xor(dep, m);
  }
  const float se = 1.0f / fmaxf(sqrtf(sse), 1e-8f);
  const float sp = 1.0f / fmaxf(sqrtf(ssp), 1e-8f);
  const float sn = 1.0f / fmaxf(sqrtf(ssn), 1e-8f);

  int ue = __builtin_amdgcn_cvt_pk_fp8_f32(ev.x*se, ev.y*se, 0, false);
  ue     = __builtin_amdgcn_cvt_pk_fp8_f32(ev.z*se, ev.w*se, ue, true);
  int up = __builtin_amdgcn_cvt_pk_fp8_f32(pv.x*sp, pv.y*sp, 0, false);
  up     = __builtin_amdgcn_cvt_pk_fp8_f32(pv.z*sp, pv.w*sp, up, true);
  int un = __builtin_amdgcn_cvt_pk_fp8_f32(nv.x*sn, nv.y*sn, 0, false);
  un     = __builtin_amdgcn_cvt_pk_fp8_f32(nv.z*sn, nv.w*sn, un, true);
  eb[row * 64 + lane] = (uint32_t)ue;
  pb[row * 64 + lane] = (uint32_t)up;
  nb[row * 64 + lane] = (uint32_t)un;

  if (lane == 0) cbuf[row] = dep * se * sp * INV_T;
}

// Kernel 2: 128x128-tile fp8 GEMM (X @ Y^T) using MX-scaled MFMA 16x16x128_f8f6f4
// (unit scales 0x7F => plain fp8 math at ~2x the non-scaled fp8 rate), BK=128,
// 2 pipelined k-iters, 4 waves of 4x4 16x16-tiles (64x64/wave), fused exp row-sums.
// LDS swizzle: 16B-group gg of row r at slot gg ^ (r&7); storage-only permutation,
// logical k order identical for A and B.
__global__ __launch_bounds__(256, 4) void simexp_kernel(
    const uint8_t* __restrict__ eb, const uint8_t* __restrict__ pb,
    const uint8_t* __restrict__ nb, const float* __restrict__ cbuf,
    float* __restrict__ part) {
  __shared__ uint8_t As[BM * BK];   // 16 KB
  __shared__ uint8_t Bs[BN * BK];   // 16 KB
  __shared__ float cs[BM];          // 512 B -> 4 blocks/CU by LDS

  const int z = blockIdx.z;
  const uint8_t* __restrict__ A = z ? pb : eb;
  const uint8_t* __restrict__ B = z ? eb : nb;

  const int tid = threadIdx.x;
  const int wave = tid >> 6, lane = tid & 63;
  const int lane15 = lane & 15, quad = lane >> 4;
  const int wr = wave & 1, wc = wave >> 1;
  const int rowTile = blockIdx.x * BM, colblk = blockIdx.y;
  const int colTile = colblk * BN;

  if (tid < BM) cs[tid] = cbuf[rowTile + tid];

  f32x4 acc[4][4];
#pragma unroll
  for (int mi = 0; mi < 4; ++mi)
#pragma unroll
    for (int ni = 0; ni < 4; ++ni)
      acc[mi][ni] = (f32x4){0.f, 0.f, 0.f, 0.f};

  const int g0 = quad * 2;                        // lane's first logical 16B-group

#pragma unroll
  for (int ks = 0; ks < 2; ++ks) {
    if (ks) __syncthreads();                      // LDS reuse guard
#pragma unroll
    for (int t = 0; t < 4; ++t) {                 // 1024 chunks per operand, 4/thread
      const int c = t * 256 + tid;
      const int r = c >> 3, sl = c & 7;
      const int gg = sl ^ (r & 7);                // swizzled SOURCE group
      const size_t off = (size_t)r * D + ks * BK + gg * 16;
      __builtin_amdgcn_global_load_lds((gbl_u32*)(A + (size_t)rowTile * D + off),
                                       (lds_u32*)&As[c * 16], 16, 0, 0);
      __builtin_amdgcn_global_load_lds((gbl_u32*)(B + (size_t)colTile * D + off),
                                       (lds_u32*)&Bs[c * 16], 16, 0, 0);
    }
    __syncthreads();                              // drain -> tiles visible

    i32x8 af[4];
#pragma unroll
    for (int mi = 0; mi < 4; ++mi) {
      const int rl = wr * 64 + mi * 16 + lane15;
      const int s = rl & 7;
      const i32x4 lo = *(const i32x4*)&As[rl * BK + ((g0 ^ s) * 16)];
      const i32x4 hi = *(const i32x4*)&As[rl * BK + (((g0 + 1) ^ s) * 16)];
      af[mi] = __builtin_shufflevector(lo, hi, 0, 1, 2, 3, 4, 5, 6, 7);
    }
#pragma unroll
    for (int ni = 0; ni < 4; ++ni) {
      const int cl = wc * 64 + ni * 16 + lane15;
      const int s = cl & 7;
      const i32x4 lo = *(const i32x4*)&Bs[cl * BK + ((g0 ^ s) * 16)];
      const i32x4 hi = *(const i32x4*)&Bs[cl * BK + (((g0 + 1) ^ s) * 16)];
      const i32x8 bf = __builtin_shufflevector(lo, hi, 0, 1, 2, 3, 4, 5, 6, 7);
#pragma unroll
      for (int mi = 0; mi < 4; ++mi)
        acc[mi][ni] = __builtin_amdgcn_mfma_scale_f32_16x16x128_f8f6f4(
            af[mi], bf, acc[mi][ni], 0, 0, 0, 127, 0, 127);
    }
  }

  // Epilogue. 16x16 C/D: col=lane&15, row=quad*4+reg (shape-determined, m121-128).
#pragma unroll
  for (int mi = 0; mi < 4; ++mi) {
    const int rbase = wr * 64 + mi * 16 + quad * 4;
#pragma unroll
    for (int reg = 0; reg < 4; ++reg) {
      const int rowl = rbase + reg;
      const float cv = cs[rowl];
      float v = __expf(acc[mi][0][reg] * INV_T - cv) +
                __expf(acc[mi][1][reg] * INV_T - cv) +
                __expf(acc[mi][2][reg] * INV_T - cv) +
                __expf(acc[mi][3][reg] * INV_T - cv);
      v += __shfl_xor(v, 1);
      v += __shfl_xor(v, 2);
      v += __shfl_xor(v, 4);
      v += __shfl_xor(v, 8);
      if (lane15 == 0)
        part[((size_t)(z * 128 + colblk * 2 + wc)) * N + rowTile + rowl] = v;
    }
  }
}

// Kernel 3: per-row sum of 128 partials -> log/log1p -> block reduce -> atomicAdd(out).
// 256 blocks; block handles 64 row-items; thread (t&63)=item, (t>>6)=quarter of parts.
__global__ __launch_bounds__(256) void reduce_kernel(const float* __restrict__ part,
                                                     float* __restrict__ out) {
  __shared__ float sm[64][4];
  const int tid = threadIdx.x;
  const int item0 = blockIdx.x * 64;               // items: z*N + row, 16384 total
  const int il = tid & 63, seg = tid >> 6;
  const int item = item0 + il;
  const int z = item >> 13, row = item & (N - 1);
  float s = 0.0f;
#pragma unroll 8
  for (int x = seg * 32; x < seg * 32 + 32; ++x)
    s += part[((size_t)(z * 128 + x)) * N + row];
  sm[il][seg] = s;
  __syncthreads();
  if (tid < 64) {
    const float t = sm[tid][0] + sm[tid][1] + sm[tid][2] + sm[tid][3];
    const int zz = (item0 + tid) >> 13;
    float val = zz ? logf(t) : log1pf(t);
#pragma unroll
    for (int m = 1; m < 64; m <<= 1) val += __shfl_xor(val, m);
    if (tid == 0) atomicAdd(out, val * (1.0f / (float)N));
  }
}

extern "C" void kernel_launch(void* const* d_in, const int* in_sizes, int n_in,
                              void* d_out, int out_size, void* d_ws, size_t ws_size,
                              hipStream_t stream) {
  const float* e = (const float*)d_in[0];
  const float* p = (const float*)d_in[1];
  const float* n = (const float*)d_in[2];

  char* w = (char*)d_ws;
  uint8_t* eb = (uint8_t*)w;                                     // 2 MB
  uint8_t* pb = eb + (size_t)N * D;                              // 2 MB
  uint8_t* nb = pb + (size_t)N * D;                              // 2 MB
  float* cbuf = (float*)(nb + (size_t)N * D);                    // 32 KB
  float* part = cbuf + N;                                        // 2*128*8192*4 = 8 MB
  float* out = (float*)d_out;

  normalize_kernel<<<N / 4, 256, 0, stream>>>(e, p, n, (uint32_t*)eb, (uint32_t*)pb,
                                              (uint32_t*)nb, cbuf, out);
  simexp_kernel<<<dim3(N / BM, N / BN, 2), 256, 0, stream>>>(eb, pb, nb, cbuf, part);
  reduce_kernel<<<256, 256, 0, stream>>>(part, out);
}